// Round 2
// baseline (367.351 us; speedup 1.0000x reference)
//
#include <hip/hip_runtime.h>

#define SS 512
#define CC 128
#define RR (SS*SS)   // 262144

typedef unsigned short u16;
typedef unsigned int   u32;
typedef __attribute__((ext_vector_type(4))) float f32x4;
typedef __attribute__((ext_vector_type(8))) short s16x8;
typedef __attribute__((ext_vector_type(4))) u32   u32x4;

__device__ __forceinline__ float bf2f(u16 u){ u32 x = ((u32)u)<<16; float f; __builtin_memcpy(&f,&x,4); return f; }
__device__ __forceinline__ u16 f2bf(float f){ u32 x; __builtin_memcpy(&x,&f,4); x += 0x7fffu + ((x>>16)&1u); return (u16)(x>>16); }
__device__ __forceinline__ float sigf(float x){ return 1.f/(1.f + __expf(-x)); }

typedef __attribute__((address_space(1))) void* gptr_t;
typedef __attribute__((address_space(3))) void* lptr_t;
__device__ __forceinline__ void load_lds16(const void* g, void* l){
  __builtin_amdgcn_global_load_lds((gptr_t)(g), (lptr_t)(l), 16, 0, 0);
}

// ---------------------------------------------------------------------------
// K1: z -> LN -> {sigmoid(zn@wa^T) as a_t(c,r), sigmoid(zn@wb^T) as b_t(c,r),
//                 sigmoid(zn@wg^T) as g(r,c)}   (r = flat row in 0..262143)
// ---------------------------------------------------------------------------
__global__ __launch_bounds__(256,2) void k1(
    const float* __restrict__ z, const float* __restrict__ lnw, const float* __restrict__ lnb,
    const float* __restrict__ wa, const float* __restrict__ wb, const float* __restrict__ wg,
    u16* __restrict__ a_t, u16* __restrict__ b_t, u16* __restrict__ g_out)
{
  __shared__ u16 zn[64][136];   // normalized rows, bf16
  __shared__ u16 wk[128][40];   // one 32-wide K-slice of W, bf16 (rows = out chan)
  __shared__ u16 tr[128*72];    // transpose staging (also viewed as [64][136] for g)
  const int tid = threadIdx.x;
  const int r0  = blockIdx.x * 64;
  const int lane = tid & 63, w = tid >> 6;

  // ---- LayerNorm: 4 threads per row ----
  {
    int row = tid >> 2, q = tid & 3;
    const float* src = z + (size_t)(r0+row)*CC + q*32;
    float v[32]; float s = 0.f, s2 = 0.f;
    #pragma unroll
    for (int i=0;i<8;i++){
      f32x4 t = *reinterpret_cast<const f32x4*>(src + i*4);
      #pragma unroll
      for (int e=0;e<4;e++){ float x = t[e]; v[i*4+e]=x; s += x; s2 += x*x; }
    }
    s  += __shfl_xor(s,1);  s2 += __shfl_xor(s2,1);
    s  += __shfl_xor(s,2);  s2 += __shfl_xor(s2,2);
    float mu  = s * (1.f/128.f);
    float var = s2*(1.f/128.f) - mu*mu;
    float rs  = rsqrtf(var + 1e-5f);
    #pragma unroll
    for (int i=0;i<4;i++){
      u32 pk[4];
      #pragma unroll
      for (int e=0;e<8;e+=2){
        int ci = i*8+e; int c = q*32 + ci;
        float y0 = (v[ci]  -mu)*rs*lnw[c]   + lnb[c];
        float y1 = (v[ci+1]-mu)*rs*lnw[c+1] + lnb[c+1];
        pk[e>>1] = (u32)f2bf(y0) | ((u32)f2bf(y1)<<16);
      }
      *reinterpret_cast<u32x4*>(&zn[row][q*32 + i*8]) = *reinterpret_cast<u32x4*>(pk);
    }
  }
  __syncthreads();

  const float* Ws[3] = {wa, wb, wg};
  for (int m=0;m<3;m++){
    f32x4 acc[8];
    #pragma unroll
    for (int cb=0;cb<8;cb++) acc[cb] = (f32x4){0.f,0.f,0.f,0.f};

    for (int ks=0;ks<4;ks++){
      { // stage wk[n][0..31] = W[n][ks*32 .. +32] as bf16
        int n = tid>>1, half = tid&1;
        const float* src = Ws[m] + n*CC + ks*32 + half*16;
        u32 pk[8];
        #pragma unroll
        for (int v4=0; v4<4; v4++){
          f32x4 t = *reinterpret_cast<const f32x4*>(src + v4*4);
          pk[v4*2]   = (u32)f2bf(t[0]) | ((u32)f2bf(t[1])<<16);
          pk[v4*2+1] = (u32)f2bf(t[2]) | ((u32)f2bf(t[3])<<16);
        }
        *reinterpret_cast<u32x4*>(&wk[n][half*16])   = *reinterpret_cast<u32x4*>(pk);
        *reinterpret_cast<u32x4*>(&wk[n][half*16+8]) = *reinterpret_cast<u32x4*>(pk+4);
      }
      __syncthreads();
      s16x8 af = *reinterpret_cast<const s16x8*>(&zn[w*16 + (lane&15)][ks*32 + (lane>>4)*8]);
      #pragma unroll
      for (int cb=0;cb<8;cb++){
        s16x8 bf = *reinterpret_cast<const s16x8*>(&wk[cb*16 + (lane&15)][(lane>>4)*8]);
        acc[cb] = __builtin_amdgcn_mfma_f32_16x16x32_bf16(af, bf, acc[cb], 0,0,0);
      }
      __syncthreads();
    }

    if (m < 2){
      // sigmoid -> bf16 -> LDS transpose [col][row] (stride 72) -> coalesced global
      #pragma unroll
      for (int cb=0;cb<8;cb++){
        int col = cb*16 + (lane&15);
        int rbase = w*16 + (lane>>4)*4;
        u32 p0 = (u32)f2bf(sigf(acc[cb][0])) | ((u32)f2bf(sigf(acc[cb][1]))<<16);
        u32 p1 = (u32)f2bf(sigf(acc[cb][2])) | ((u32)f2bf(sigf(acc[cb][3]))<<16);
        u32* d = reinterpret_cast<u32*>(&tr[col*72 + rbase]);
        d[0] = p0; d[1] = p1;
      }
      __syncthreads();
      {
        // each thread writes ALL 32 rows of its (channel c, half) block
        int c = tid>>1, half = tid&1;
        u16* dst = (m==0 ? a_t : b_t) + ((size_t)c<<18) + r0 + half*32;
        const u16* srcl = &tr[c*72 + half*32];
        #pragma unroll
        for (int e=0;e<4;e++)
          *reinterpret_cast<u32x4*>(dst + e*8) = *reinterpret_cast<const u32x4*>(srcl + e*8);
      }
      __syncthreads();
    } else {
      // g: stage [row][col] (stride 136) then coalesced row-major write
      u16* gb = &tr[0];
      #pragma unroll
      for (int cb=0;cb<8;cb++){
        int col = cb*16 + (lane&15);
        int rbase = w*16 + (lane>>4)*4;
        #pragma unroll
        for (int q=0;q<4;q++)
          gb[(rbase+q)*136 + col] = f2bf(sigf(acc[cb][q]));
      }
      __syncthreads();
      {
        int row = tid>>2, qo = tid&3;
        u16* dst = g_out + (size_t)(r0+row)*CC + qo*32;
        const u16* srcl = &gb[row*136 + qo*32];
        #pragma unroll
        for (int e=0;e<4;e++)
          *reinterpret_cast<u32x4*>(dst + e*8) = *reinterpret_cast<const u32x4*>(srcl + e*8);
      }
    }
  }
}

// ---------------------------------------------------------------------------
// K1b: b_t (c,k,j) -> bT (c,j,k)   64x64 LDS-tiled transpose per channel
// ---------------------------------------------------------------------------
__global__ __launch_bounds__(256,4) void k1b(const u16* __restrict__ b_t, u16* __restrict__ bT)
{
  __shared__ u16 tile[64][72];
  const int tid = threadIdx.x;
  const int c  = blockIdx.x >> 6;
  const int t  = blockIdx.x & 63;
  const int k0 = (t>>3)*64, j0 = (t&7)*64;
  const u16* src = b_t + ((size_t)c<<18);
  {
    int row = tid>>3, chunk = tid&7;
    #pragma unroll
    for (int pass=0; pass<2; pass++){
      int k = row + pass*32;
      const u16* s = src + (size_t)(k0+k)*SS + j0 + chunk*8;
      u32x4 v = *reinterpret_cast<const u32x4*>(s);
      int cs = chunk ^ ((k>>3)&7);
      *reinterpret_cast<u32x4*>(&tile[k][cs*8]) = v;
    }
  }
  __syncthreads();
  {
    int j = tid>>2, part = tid&3;
    u32 pk[8];
    #pragma unroll
    for (int i=0;i<16;i+=2){
      int ka = part*16 + i;
      int key = (ka>>3)&7;
      u16 va = tile[ka  ][(((j>>3)^key)*8) + (j&7)];
      u16 vb = tile[ka+1][(((j>>3)^key)*8) + (j&7)];
      pk[i>>1] = (u32)va | ((u32)vb<<16);
    }
    u16* dst = bT + ((size_t)c<<18) + (size_t)(j0+j)*SS + k0 + part*16;
    *reinterpret_cast<u32x4*>(dst)   = *reinterpret_cast<u32x4*>(pk);
    *reinterpret_cast<u32x4*>(dst+8) = *reinterpret_cast<u32x4*>(pk+4);
  }
}

// ---------------------------------------------------------------------------
// K2: per-channel GEMM  p_c = A_c @ B_c   (A = a_t rows i, bT rows j; both K-contig)
// 128x128 tile, BK=64, global_load_lds w16, XOR-swizzled LDS, A double-buffered
// ---------------------------------------------------------------------------
__global__ __launch_bounds__(256,2) void k2(const u16* __restrict__ a_t, const u16* __restrict__ bT,
                                            float* __restrict__ p)
{
  __shared__ u16 As[2][128*64];
  __shared__ u16 Bs[128*64];
  const int tid = threadIdx.x;
  const int lane = tid & 63, w = tid >> 6;
  const int c  = blockIdx.y;
  const int i0 = (blockIdx.x >> 2) * 128, j0 = (blockIdx.x & 3) * 128;
  const u16* Ag = a_t + ((size_t)c<<18);
  const u16* Bg = bT  + ((size_t)c<<18);
  const int pr = lane>>3, slot = lane&7;

  auto stageA = [&](int kt, int buf){
    #pragma unroll
    for (int s=0;s<4;s++){
      int rbase = w*32 + s*8;
      int rl = rbase + pr;
      const u16* g = Ag + (size_t)(i0+rl)*SS + kt*64 + ((slot^pr)*8);
      load_lds16((const void*)g, (void*)&As[buf][rbase*64]);
    }
  };
  auto stageB = [&](int kt){
    #pragma unroll
    for (int s=0;s<4;s++){
      int rbase = w*32 + s*8;
      int rl = rbase + pr;
      const u16* g = Bg + (size_t)(j0+rl)*SS + kt*64 + ((slot^pr)*8);
      load_lds16((const void*)g, (void*)&Bs[rbase*64]);
    }
  };

  f32x4 acc[4][4];
  #pragma unroll
  for (int a=0;a<4;a++)
    #pragma unroll
    for (int b=0;b<4;b++) acc[a][b] = (f32x4){0.f,0.f,0.f,0.f};
  const int wr = w>>1, wc = w&1;

  stageA(0, 0);
  for (int kt=0; kt<8; ++kt){
    stageB(kt);
    if (kt < 7){
      stageA(kt+1, (kt+1)&1);
      asm volatile("s_waitcnt vmcnt(4)" ::: "memory");
    } else {
      asm volatile("s_waitcnt vmcnt(0)" ::: "memory");
    }
    __builtin_amdgcn_s_barrier();
    const u16* Ab = &As[kt&1][0];
    #pragma unroll
    for (int ks=0;ks<2;ks++){
      s16x8 af[4], bfv[4];
      #pragma unroll
      for (int f=0; f<4; f++){
        int i = wr*64 + f*16 + (lane&15);
        int ch = (ks*4 + (lane>>4)) ^ (i&7);
        af[f] = *reinterpret_cast<const s16x8*>(&Ab[i*64 + ch*8]);
        int j = wc*64 + f*16 + (lane&15);
        int chb = (ks*4 + (lane>>4)) ^ (j&7);
        bfv[f] = *reinterpret_cast<const s16x8*>(&Bs[j*64 + chb*8]);
      }
      #pragma unroll
      for (int fi=0;fi<4;fi++)
        #pragma unroll
        for (int fj=0;fj<4;fj++)
          acc[fi][fj] = __builtin_amdgcn_mfma_f32_16x16x32_bf16(af[fi], bfv[fj], acc[fi][fj], 0,0,0);
    }
    asm volatile("s_waitcnt lgkmcnt(0)" ::: "memory");
    __builtin_amdgcn_s_barrier();
  }

  float* P = p + ((size_t)c<<18);
  #pragma unroll
  for (int fi=0;fi<4;fi++){
    int rbase = i0 + wr*64 + fi*16 + (lane>>4)*4;
    #pragma unroll
    for (int fj=0;fj<4;fj++){
      int col = j0 + wc*64 + fj*16 + (lane&15);
      #pragma unroll
      for (int q=0;q<4;q++)
        P[(size_t)(rbase+q)*SS + col] = acc[fi][fj][q];
    }
  }
}

// ---------------------------------------------------------------------------
// K3: out[r][o] = g[r][o] * (LN_c(p[. ,r]) @ wf^T)[o]
// ---------------------------------------------------------------------------
__global__ __launch_bounds__(256,2) void k3(const float* __restrict__ p, const u16* __restrict__ g,
    const float* __restrict__ flnw, const float* __restrict__ flnb,
    const float* __restrict__ wf, float* __restrict__ out)
{
  __shared__ u16 znp[64][136];
  __shared__ u16 wk[128][40];
  __shared__ float red[4][64];
  __shared__ float muv[64], rsv[64];
  const int tid = threadIdx.x;
  const int rr0 = blockIdx.x * 64;
  const int lane = tid&63, w = tid>>6;
  const int pos = tid & 63, cq = tid >> 6;

  float pv[32];
  {
    const float* src = p + rr0 + pos;
    float s = 0.f;
    #pragma unroll
    for (int ci=0;ci<32;ci++){
      int c = cq*32 + ci;
      float x = src[((size_t)c)<<18];
      pv[ci] = x; s += x;
    }
    red[cq][pos] = s;
  }
  __syncthreads();
  if (tid < 64) muv[tid] = (red[0][tid]+red[1][tid]+red[2][tid]+red[3][tid]) * (1.f/128.f);
  __syncthreads();
  float mu = muv[pos];
  {
    float s2 = 0.f;
    #pragma unroll
    for (int ci=0;ci<32;ci++){ float d = pv[ci]-mu; s2 += d*d; }
    red[cq][pos] = s2;
  }
  __syncthreads();
  if (tid < 64) rsv[tid] = rsqrtf((red[0][tid]+red[1][tid]+red[2][tid]+red[3][tid])*(1.f/128.f) + 1e-5f);
  __syncthreads();
  float rs = rsv[pos];
  {
    u32 pk[4];
    #pragma unroll
    for (int ii=0;ii<4;ii++){
      #pragma unroll
      for (int e=0;e<8;e+=2){
        int ci = ii*8+e; int c = cq*32+ci;
        float y0 = (pv[ci]  -mu)*rs*flnw[c]   + flnb[c];
        float y1 = (pv[ci+1]-mu)*rs*flnw[c+1] + flnb[c+1];
        pk[e>>1] = (u32)f2bf(y0) | ((u32)f2bf(y1)<<16);
      }
      *reinterpret_cast<u32x4*>(&znp[pos][cq*32 + ii*8]) = *reinterpret_cast<u32x4*>(pk);
    }
  }
  __syncthreads();

  f32x4 acc[8];
  #pragma unroll
  for (int cb=0;cb<8;cb++) acc[cb] = (f32x4){0.f,0.f,0.f,0.f};
  for (int ks=0;ks<4;ks++){
    { int n = tid>>1, half = tid&1;
      const float* src = wf + n*CC + ks*32 + half*16;
      u32 pk[8];
      #pragma unroll
      for (int v4=0; v4<4; v4++){
        f32x4 t = *reinterpret_cast<const f32x4*>(src + v4*4);
        pk[v4*2]   = (u32)f2bf(t[0]) | ((u32)f2bf(t[1])<<16);
        pk[v4*2+1] = (u32)f2bf(t[2]) | ((u32)f2bf(t[3])<<16);
      }
      *reinterpret_cast<u32x4*>(&wk[n][half*16])   = *reinterpret_cast<u32x4*>(pk);
      *reinterpret_cast<u32x4*>(&wk[n][half*16+8]) = *reinterpret_cast<u32x4*>(pk+4);
    }
    __syncthreads();
    s16x8 af = *reinterpret_cast<const s16x8*>(&znp[w*16 + (lane&15)][ks*32 + (lane>>4)*8]);
    #pragma unroll
    for (int cb=0;cb<8;cb++){
      s16x8 bf = *reinterpret_cast<const s16x8*>(&wk[cb*16 + (lane&15)][(lane>>4)*8]);
      acc[cb] = __builtin_amdgcn_mfma_f32_16x16x32_bf16(af, bf, acc[cb], 0,0,0);
    }
    __syncthreads();
  }

  // stage g tile into znp storage (reused), then multiply & write out
  u16* gb = &znp[0][0];
  {
    int row = tid>>2, qo = tid&3;
    const u16* src = g + (size_t)(rr0+row)*CC + qo*32;
    #pragma unroll
    for (int e=0;e<4;e++)
      *reinterpret_cast<u32x4*>(&gb[row*136 + qo*32 + e*8]) = *reinterpret_cast<const u32x4*>(src + e*8);
  }
  __syncthreads();
  #pragma unroll
  for (int cb=0;cb<8;cb++){
    int col = cb*16 + (lane&15);
    int rbase = w*16 + (lane>>4)*4;
    #pragma unroll
    for (int q=0;q<4;q++){
      float gv = bf2f(gb[(rbase+q)*136 + col]);
      out[(size_t)(rr0+rbase+q)*CC + col] = gv * acc[cb][q];
    }
  }
}

// ---------------------------------------------------------------------------
extern "C" void kernel_launch(void* const* d_in, const int* in_sizes, int n_in,
                              void* d_out, int out_size, void* d_ws, size_t ws_size,
                              hipStream_t stream)
{
  const float* z    = (const float*)d_in[0];
  const float* lnw  = (const float*)d_in[1];
  const float* lnb  = (const float*)d_in[2];
  const float* wa   = (const float*)d_in[3];
  const float* wb   = (const float*)d_in[4];
  const float* wg   = (const float*)d_in[5];
  const float* flnw = (const float*)d_in[6];
  const float* flnb = (const float*)d_in[7];
  const float* wf   = (const float*)d_in[8];
  float* out = (float*)d_out;

  char* ws = (char*)d_ws;
  u16* a_t = (u16*)(ws);                       // 64 MB  (c,i,k) bf16
  u16* bT  = (u16*)(ws + ((size_t)64<<20));    // 64 MB  (c,j,k) bf16
  u16* g   = (u16*)(ws + ((size_t)128<<20));   // 64 MB  (r,c)   bf16
  float* p = (float*)(ws + ((size_t)192<<20)); // 128 MB (c,i,j) fp32
  u16* b_t = (u16*)(ws + ((size_t)192<<20));   // 64 MB  (c,k,j) bf16 — aliases p, dead before K2

  k1 <<<4096, 256, 0, stream>>>(z, lnw, lnb, wa, wb, wg, a_t, b_t, g);
  k1b<<<8192, 256, 0, stream>>>(b_t, bT);
  k2 <<<dim3(16,128), 256, 0, stream>>>(a_t, bT, p);
  k3 <<<4096, 256, 0, stream>>>(p, g, flnw, flnb, wf, out);
}